// Round 1
// baseline (741.100 us; speedup 1.0000x reference)
//
#include <hip/hip_runtime.h>
#include <math.h>

#define LSEQ 1024
#define DM   768
#define NS   16
#define DR   48
#define BSZ  2

// ---------------- GEMM: 64x64 tile, 256 threads, 4x4 micro-tile, f32 ----------------
__global__ __launch_bounds__(256) void gemm64(const float* __restrict__ A,
                                              const float* __restrict__ B,
                                              float* __restrict__ C,
                                              int K, int lda, int ldb, int ldc) {
    __shared__ float As[16][64];   // [k][m]
    __shared__ float Bs[16][64];   // [k][n]
    const int tid = threadIdx.x;
    const int row0 = blockIdx.y * 64, col0 = blockIdx.x * 64;
    const int tx = tid & 15, ty = tid >> 4;
    const int am = tid >> 2, ak = (tid & 3) * 4;   // A staging: row am, k-quad ak
    const int bk = tid >> 4, bn = (tid & 15) * 4;  // B staging: k-row bk, col-quad bn

    float acc[4][4] = {};

    for (int k0 = 0; k0 < K; k0 += 16) {
        float4 av = *(const float4*)(A + (size_t)(row0 + am) * lda + k0 + ak);
        float4 bv = *(const float4*)(B + (size_t)(k0 + bk) * ldb + col0 + bn);
        As[ak + 0][am] = av.x;
        As[ak + 1][am] = av.y;
        As[ak + 2][am] = av.z;
        As[ak + 3][am] = av.w;
        *(float4*)&Bs[bk][bn] = bv;
        __syncthreads();
        #pragma unroll
        for (int kk = 0; kk < 16; ++kk) {
            float4 a4 = *(const float4*)&As[kk][ty * 4];
            float4 b4 = *(const float4*)&Bs[kk][tx * 4];
            float ar[4] = {a4.x, a4.y, a4.z, a4.w};
            float br[4] = {b4.x, b4.y, b4.z, b4.w};
            #pragma unroll
            for (int i = 0; i < 4; ++i)
                #pragma unroll
                for (int j = 0; j < 4; ++j)
                    acc[i][j] += ar[i] * br[j];
        }
        __syncthreads();
    }
    #pragma unroll
    for (int i = 0; i < 4; ++i) {
        float4 o = make_float4(acc[i][0], acc[i][1], acc[i][2], acc[i][3]);
        *(float4*)(C + (size_t)(row0 + ty * 4 + i) * ldc + col0 + tx * 4) = o;
    }
}

// ---------------- GEMM: 16x16 tile (for small-N xp = u @ W_x) ----------------
__global__ __launch_bounds__(256) void gemm16(const float* __restrict__ A,
                                              const float* __restrict__ B,
                                              float* __restrict__ C,
                                              int K, int lda, int ldb, int ldc) {
    __shared__ float As[16][17];
    __shared__ float Bs[16][17];
    const int tx = threadIdx.x, ty = threadIdx.y;
    const int row = blockIdx.y * 16 + ty;
    const int col = blockIdx.x * 16 + tx;
    float acc = 0.f;
    for (int k0 = 0; k0 < K; k0 += 16) {
        As[ty][tx] = A[(size_t)row * lda + k0 + tx];
        Bs[ty][tx] = B[(size_t)(k0 + ty) * ldb + col];
        __syncthreads();
        #pragma unroll
        for (int kk = 0; kk < 16; ++kk)
            acc += As[ty][kk] * Bs[kk][tx];
        __syncthreads();
    }
    C[(size_t)row * ldc + col] = acc;
}

// ---------------- depthwise causal conv (K=4) + SiLU ----------------
__global__ __launch_bounds__(256) void conv_silu(const float* __restrict__ xr,
                                                 const float* __restrict__ cw,
                                                 const float* __restrict__ cb,
                                                 float* __restrict__ u) {
    const int idx = blockIdx.x * 256 + threadIdx.x;  // r*DM + d
    const int r = idx / DM;
    const int d = idx - r * DM;
    const int l = r & (LSEQ - 1);
    float acc = cb[d];
    #pragma unroll
    for (int k = 0; k < 4; ++k) {
        int ll = l - 3 + k;
        if (ll >= 0)
            acc += xr[(size_t)(r - 3 + k) * (2 * DM) + d] * cw[d * 4 + k];
    }
    float sig = 1.f / (1.f + expf(-acc));
    u[idx] = acc * sig;
}

// ---------------- delta = clip(softplus(xp[:,:48] @ W_delta + b_delta)) ----------------
__global__ __launch_bounds__(256) void delta_kernel(const float* __restrict__ xp,
                                                    const float* __restrict__ Wd,
                                                    const float* __restrict__ bd,
                                                    float* __restrict__ delta) {
    __shared__ float s[48];
    const int r = blockIdx.y;
    const int c = blockIdx.x * 256 + threadIdx.x;
    if (threadIdx.x < 48) s[threadIdx.x] = xp[(size_t)r * 80 + threadIdx.x];
    __syncthreads();
    float acc = bd[c];
    #pragma unroll
    for (int k = 0; k < 48; ++k)
        acc += s[k] * Wd[k * DM + c];
    float sp = (acc > 20.f) ? acc : log1pf(expf(acc));
    sp = fminf(fmaxf(sp, 1e-4f), 0.1f);
    delta[(size_t)r * DM + c] = sp;
}

// ---------------- selective scan + gate ----------------
// Block: 256 threads = 16 d_sub x 16 n. Grid: BSZ * (DM/16) = 96 blocks.
// Replicates reference numerics: xs[l] = h[l] / (1 + 1e-12*exp(-S[l])),
// h[l] = exp(dA[l])*h[l-1] + delta*u*B;  S[l] = a*(sumDelta - prefixDelta).
__global__ __launch_bounds__(256) void scan_kernel(const float* __restrict__ delta,
                                                   const float* __restrict__ u,
                                                   const float* __restrict__ xp,
                                                   const float* __restrict__ xr,
                                                   const float* __restrict__ A_log,
                                                   const float* __restrict__ Dp,
                                                   float* __restrict__ g) {
    __shared__ float sD[64][16];
    __shared__ float sU[64][16];
    __shared__ float sB[64][16];
    __shared__ float sC[64][16];
    __shared__ float sR[64][16];

    const int tid = threadIdx.x;
    const int n  = tid & 15;
    const int ds = tid >> 4;
    const int blk = blockIdx.x;
    const int b  = blk / (DM / 16);
    const int d0 = (blk % (DM / 16)) * 16;
    const int d  = d0 + ds;

    const float a  = -expf(A_log[d * NS + n]);
    const float dp = Dp[d];

    // ---- pass A: TD = sum over l of delta[b,l,d] ----
    float TD = 0.f;
    for (int c0 = 0; c0 < LSEQ; c0 += 64) {
        #pragma unroll
        for (int j = 0; j < 4; ++j) {
            int i = tid + j * 256;
            int l = i >> 4, dd = i & 15;
            sD[l][dd] = delta[(size_t)(b * LSEQ + c0 + l) * DM + d0 + dd];
        }
        __syncthreads();
        #pragma unroll 4
        for (int l = 0; l < 64; ++l) TD += sD[l][ds];
        __syncthreads();
    }

    // ---- pass B: forward recurrence ----
    float PD = 0.f, h = 0.f;
    for (int c0 = 0; c0 < LSEQ; c0 += 64) {
        #pragma unroll
        for (int j = 0; j < 4; ++j) {
            int i = tid + j * 256;
            int l = i >> 4, dd = i & 15;
            size_t r = (size_t)(b * LSEQ + c0 + l);
            sD[l][dd] = delta[r * DM + d0 + dd];
            sU[l][dd] = u[r * DM + d0 + dd];
            sB[l][dd] = xp[r * 80 + DR + dd];
            sC[l][dd] = xp[r * 80 + DR + NS + dd];
            sR[l][dd] = xr[r * (2 * DM) + DM + d0 + dd];
        }
        __syncthreads();
        for (int l = 0; l < 64; ++l) {
            float dlt = sD[l][ds];
            float uu  = sU[l][ds];
            PD += dlt;
            float dA = dlt * a;
            float e  = expf(dA);
            h = e * h + dlt * uu * sB[l][n];
            float S = a * (TD - PD);                 // = sum_{j>l} dA[j]
            float corr = 1.0f / (1.0f + 1e-12f * expf(-S));  // exp overflow -> corr=0, matches ref
            float contrib = h * corr * sC[l][n];
            contrib += __shfl_xor(contrib, 1);
            contrib += __shfl_xor(contrib, 2);
            contrib += __shfl_xor(contrib, 4);
            contrib += __shfl_xor(contrib, 8);
            if (n == 0) {
                float y = contrib + uu * dp;
                float rr = sR[l][ds];
                float sig = 1.f / (1.f + expf(-rr));
                g[(size_t)(b * LSEQ + c0 + l) * DM + d] = y * rr * sig;
            }
        }
        __syncthreads();
    }
}

extern "C" void kernel_launch(void* const* d_in, const int* in_sizes, int n_in,
                              void* d_out, int out_size, void* d_ws, size_t ws_size,
                              hipStream_t stream) {
    const float* x       = (const float*)d_in[0];
    const float* W_in    = (const float*)d_in[1];
    const float* conv_w  = (const float*)d_in[2];
    const float* conv_b  = (const float*)d_in[3];
    const float* W_x     = (const float*)d_in[4];
    const float* W_delta = (const float*)d_in[5];
    const float* b_delta = (const float*)d_in[6];
    const float* A_log   = (const float*)d_in[7];
    const float* D_param = (const float*)d_in[8];
    const float* W_out   = (const float*)d_in[9];
    float* out = (float*)d_out;
    float* ws  = (float*)d_ws;

    const int R = BSZ * LSEQ;  // 2048

    float* xr    = ws;                          // R*1536
    float* u     = xr    + (size_t)R * 1536;    // R*768
    float* xp    = u     + (size_t)R * 768;     // R*80
    float* delta = xp    + (size_t)R * 80;      // R*768
    float* g     = delta + (size_t)R * 768;     // R*768

    // 1) xr = x @ W_in   (2048 x 1536, K=768)
    gemm64<<<dim3(1536 / 64, R / 64), 256, 0, stream>>>(x, W_in, xr, 768, 768, 1536, 1536);
    // 2) u = silu(causal depthwise conv(xr[:, :768]) + conv_b)
    conv_silu<<<(R * DM) / 256, 256, 0, stream>>>(xr, conv_w, conv_b, u);
    // 3) xp = u @ W_x    (2048 x 80, K=768)
    gemm16<<<dim3(80 / 16, R / 16), dim3(16, 16), 0, stream>>>(u, W_x, xp, 768, 768, 80, 80);
    // 4) delta = clip(softplus(xp[:, :48] @ W_delta + b_delta))
    delta_kernel<<<dim3(3, R), 256, 0, stream>>>(xp, W_delta, b_delta, delta);
    // 5) selective scan + D skip + gate with silu(res)
    scan_kernel<<<BSZ * (DM / 16), 256, 0, stream>>>(delta, u, xp, xr, A_log, D_param, g);
    // 6) out = g @ W_out (2048 x 768, K=768)
    gemm64<<<dim3(768 / 64, R / 64), 256, 0, stream>>>(g, W_out, out, 768, 768, 768, 768);
}

// Round 3
// 255.724 us; speedup vs baseline: 2.8980x; 2.8980x over previous
//
#include <hip/hip_runtime.h>
#include <math.h>

#define LSEQ 1024
#define DM   768
#define NS   16
#define DR   48
#define BSZ  2
#define NC   16           // chunks over L
#define LC   (LSEQ/NC)    // 64

typedef __bf16 bf16x4 __attribute__((ext_vector_type(4)));
typedef __bf16 bf16x8 __attribute__((ext_vector_type(8)));
typedef float  f32x4  __attribute__((ext_vector_type(4)));

// ---------------- GEMM: f32 in/out, bf16 MFMA compute ----------------
// C[M,N] = A[M,K] @ B[K,N]. Tile 128x128, 256 threads = 4 waves (2x2 of 64x64),
// K-step 32, mfma_f32_16x16x32_bf16. f32->bf16 conversion happens during LDS
// staging (no pre-cast buffers -> no extra workspace).
// A-frag layout: A[m=lane&15][k=(lane>>4)*8+j]; B-frag: B[n=lane&15][k=...];
// C/D: row=(lane>>4)*4+reg, col=lane&15  (m89/m91-verified mapping).
__global__ __launch_bounds__(256) void gemm_bf16(const float* __restrict__ A,
                                                 const float* __restrict__ B,
                                                 float* __restrict__ C,
                                                 int K, int lda, int ldb, int ldc) {
    // rows padded to 40 bf16 (80 B, multiple of 16 B) -> frag ds_read_b128 2-way max
    __shared__ __align__(16) __bf16 As[128][40];   // As[m][k]
    __shared__ __align__(16) __bf16 Bs[128][40];   // Bs[n][k] (transposed in staging)
    const int tid  = threadIdx.x;
    const int lane = tid & 63;
    const int wave = tid >> 6;
    const int wr = (wave >> 1) * 64, wc = (wave & 1) * 64;
    const int r = lane & 15, q = lane >> 4;
    const int m0 = blockIdx.y * 128, n0 = blockIdx.x * 128;

    // A staging map: row = (tid>>3) + 32j, k-quad = (tid&7)*4
    const int arow = tid >> 3, ac4 = (tid & 7) * 4;
    // B staging map: each thread owns a 4x4 (k x n) transpose block.
    // nq in 0..31 (wave-aware so lanes spread banks), kg in 0..7.
    const int nq = (tid & 7) + (tid >> 6) * 8;   // n-quad
    const int kg = (tid >> 3) & 7;               // k-quad

    f32x4 zero = {0.f, 0.f, 0.f, 0.f};
    f32x4 acc[4][4];
    #pragma unroll
    for (int mt = 0; mt < 4; ++mt)
        #pragma unroll
        for (int nt = 0; nt < 4; ++nt) acc[mt][nt] = zero;

    for (int k0 = 0; k0 < K; k0 += 32) {
        // ---- stage A tile: 128 x 32 ----
        #pragma unroll
        for (int j = 0; j < 4; ++j) {
            int row = arow + 32 * j;
            f32x4 v = *(const f32x4*)(A + (size_t)(m0 + row) * lda + k0 + ac4);
            bf16x4 pk = {(__bf16)v[0], (__bf16)v[1], (__bf16)v[2], (__bf16)v[3]};
            *(bf16x4*)&As[row][ac4] = pk;
        }
        // ---- stage B tile: 32 x 128, transposed to Bs[n][k] via 4x4 reg block ----
        {
            f32x4 bv[4];
            #pragma unroll
            for (int i = 0; i < 4; ++i)
                bv[i] = *(const f32x4*)(B + (size_t)(k0 + kg * 4 + i) * ldb + n0 + nq * 4);
            #pragma unroll
            for (int c = 0; c < 4; ++c) {
                bf16x4 pk = {(__bf16)bv[0][c], (__bf16)bv[1][c],
                             (__bf16)bv[2][c], (__bf16)bv[3][c]};
                *(bf16x4*)&Bs[nq * 4 + c][kg * 4] = pk;
            }
        }
        __syncthreads();
        bf16x8 af[4], bf[4];
        #pragma unroll
        for (int t = 0; t < 4; ++t) {
            af[t] = *(const bf16x8*)&As[wr + t * 16 + r][q * 8];
            bf[t] = *(const bf16x8*)&Bs[wc + t * 16 + r][q * 8];
        }
        #pragma unroll
        for (int mt = 0; mt < 4; ++mt)
            #pragma unroll
            for (int nt = 0; nt < 4; ++nt)
                acc[mt][nt] = __builtin_amdgcn_mfma_f32_16x16x32_bf16(
                    af[mt], bf[nt], acc[mt][nt], 0, 0, 0);
        __syncthreads();
    }
    // epilogue: lane holds rows q*4+rr, col r of each 16x16 tile
    #pragma unroll
    for (int mt = 0; mt < 4; ++mt) {
        #pragma unroll
        for (int nt = 0; nt < 4; ++nt) {
            int col  = n0 + wc + nt * 16 + r;
            int rowb = m0 + wr + mt * 16 + q * 4;
            #pragma unroll
            for (int rr = 0; rr < 4; ++rr)
                C[(size_t)(rowb + rr) * ldc + col] = acc[mt][nt][rr];
        }
    }
}

// ---------------- GEMM: 16x16 tile (for small-N xp = u @ W_x), f32 ----------------
__global__ __launch_bounds__(256) void gemm16(const float* __restrict__ A,
                                              const float* __restrict__ B,
                                              float* __restrict__ C,
                                              int K, int lda, int ldb, int ldc) {
    __shared__ float As[16][17];
    __shared__ float Bs[16][17];
    const int tx = threadIdx.x, ty = threadIdx.y;
    const int row = blockIdx.y * 16 + ty;
    const int col = blockIdx.x * 16 + tx;
    float acc = 0.f;
    for (int k0 = 0; k0 < K; k0 += 16) {
        As[ty][tx] = A[(size_t)row * lda + k0 + tx];
        Bs[ty][tx] = B[(size_t)(k0 + ty) * ldb + col];
        __syncthreads();
        #pragma unroll
        for (int kk = 0; kk < 16; ++kk)
            acc += As[ty][kk] * Bs[kk][tx];
        __syncthreads();
    }
    C[(size_t)row * ldc + col] = acc;
}

// ---------------- depthwise causal conv (K=4) + SiLU ----------------
__global__ __launch_bounds__(256) void conv_silu(const float* __restrict__ xr,
                                                 const float* __restrict__ cw,
                                                 const float* __restrict__ cb,
                                                 float* __restrict__ u) {
    const int idx = blockIdx.x * 256 + threadIdx.x;  // r*DM + d
    const int r = idx / DM;
    const int d = idx - r * DM;
    const int l = r & (LSEQ - 1);
    float acc = cb[d];
    #pragma unroll
    for (int k = 0; k < 4; ++k) {
        int ll = l - 3 + k;
        if (ll >= 0)
            acc += xr[(size_t)(r - 3 + k) * (2 * DM) + d] * cw[d * 4 + k];
    }
    float sig = 1.f / (1.f + expf(-acc));
    u[idx] = acc * sig;
}

// ---------------- delta = clip(softplus(xp[:,:48] @ W_delta + b_delta)) ----------------
__global__ __launch_bounds__(256) void delta_kernel(const float* __restrict__ xp,
                                                    const float* __restrict__ Wd,
                                                    const float* __restrict__ bd,
                                                    float* __restrict__ delta) {
    __shared__ float s[48];
    const int r = blockIdx.y;
    const int c = blockIdx.x * 256 + threadIdx.x;
    if (threadIdx.x < 48) s[threadIdx.x] = xp[(size_t)r * 80 + threadIdx.x];
    __syncthreads();
    float acc = bd[c];
    #pragma unroll
    for (int k = 0; k < 48; ++k)
        acc += s[k] * Wd[k * DM + c];
    float sp = (acc > 20.f) ? acc : log1pf(expf(acc));
    sp = fminf(fmaxf(sp, 1e-4f), 0.1f);
    delta[(size_t)r * DM + c] = sp;
}

// ---------------- chunked selective scan ----------------
// grid = BSZ*(DM/16)*NC; block 256 = 16 d x 16 n
__global__ __launch_bounds__(256) void scan_part1(const float* __restrict__ delta,
                                                  const float* __restrict__ u,
                                                  const float* __restrict__ xp,
                                                  const float* __restrict__ A_log,
                                                  float* __restrict__ Eprod,
                                                  float* __restrict__ Hend,
                                                  float* __restrict__ SDel) {
    __shared__ float sD[LC][16];
    __shared__ float sU[LC][16];
    __shared__ float sB[LC][16];
    const int tid = threadIdx.x;
    const int n = tid & 15, ds = tid >> 4;
    const int blk = blockIdx.x;
    const int ch = blk % NC;
    const int dblk = (blk / NC) % (DM / 16);
    const int b = blk / (NC * (DM / 16));
    const int d0 = dblk * 16;
    const int l0 = ch * LC;
    const float a = -expf(A_log[(d0 + ds) * NS + n]);

    #pragma unroll
    for (int j = 0; j < (LC * 16) / 256; ++j) {
        int i = tid + j * 256;
        int l = i >> 4, dd = i & 15;
        size_t r = (size_t)(b * LSEQ + l0 + l);
        sD[l][dd] = delta[r * DM + d0 + dd];
        sU[l][dd] = u[r * DM + d0 + dd];
        sB[l][dd] = xp[r * 80 + DR + dd];
    }
    __syncthreads();
    float h = 0.f, ep = 1.f, pd = 0.f;
    for (int l = 0; l < LC; ++l) {
        float dlt = sD[l][ds];
        float e = expf(a * dlt);
        h = e * h + dlt * sU[l][ds] * sB[l][n];
        ep *= e;
        pd += dlt;
    }
    size_t idx = (size_t)blk * 256 + tid;
    Hend[idx] = h;
    Eprod[idx] = ep;
    if (n == 0) SDel[(size_t)blk * 16 + ds] = pd;
}

// grid = BSZ*(DM/16) = 96. Overwrites Hend with H_in, SDel with PD0.
__global__ __launch_bounds__(256) void scan_combine(const float* __restrict__ Eprod,
                                                    float* __restrict__ Hend,
                                                    float* __restrict__ SDel,
                                                    float* __restrict__ TD) {
    const int tid = threadIdx.x;
    const int base = blockIdx.x;
    float H = 0.f;
    for (int c = 0; c < NC; ++c) {
        size_t idx = ((size_t)base * NC + c) * 256 + tid;
        float e = Eprod[idx];
        float he = Hend[idx];
        Hend[idx] = H;
        H = e * H + he;
    }
    if ((tid & 15) == 0) {
        int ds = tid >> 4;
        float pd = 0.f;
        for (int c = 0; c < NC; ++c) {
            size_t si = ((size_t)base * NC + c) * 16 + ds;
            float s = SDel[si];
            SDel[si] = pd;
            pd += s;
        }
        TD[(size_t)base * 16 + ds] = pd;
    }
}

// grid = BSZ*(DM/16)*NC. NOTE: g may alias u — each block stages its u-region
// into LDS before any g-write to the identical region; no other block/kernel
// reads those u entries afterward.
__global__ __launch_bounds__(256) void scan_part3(const float* __restrict__ delta,
                                                  const float* __restrict__ u,
                                                  const float* __restrict__ xp,
                                                  const float* __restrict__ xr,
                                                  const float* __restrict__ A_log,
                                                  const float* __restrict__ Dp,
                                                  const float* __restrict__ Hin,
                                                  const float* __restrict__ PD0,
                                                  const float* __restrict__ TD,
                                                  float* __restrict__ g) {
    __shared__ float sD[LC][16];
    __shared__ float sU[LC][16];
    __shared__ float sB[LC][16];
    __shared__ float sC[LC][16];
    __shared__ float sR[LC][16];
    const int tid = threadIdx.x;
    const int n = tid & 15, ds = tid >> 4;
    const int blk = blockIdx.x;
    const int ch = blk % NC;
    const int dblk = (blk / NC) % (DM / 16);
    const int b = blk / (NC * (DM / 16));
    const int d0 = dblk * 16;
    const int l0 = ch * LC;
    const int d = d0 + ds;
    const float a = -expf(A_log[d * NS + n]);
    const float dp = Dp[d];

    #pragma unroll
    for (int j = 0; j < (LC * 16) / 256; ++j) {
        int i = tid + j * 256;
        int l = i >> 4, dd = i & 15;
        size_t r = (size_t)(b * LSEQ + l0 + l);
        sD[l][dd] = delta[r * DM + d0 + dd];
        sU[l][dd] = u[r * DM + d0 + dd];
        sB[l][dd] = xp[r * 80 + DR + dd];
        sC[l][dd] = xp[r * 80 + DR + NS + dd];
        sR[l][dd] = xr[r * (2 * DM) + DM + d0 + dd];
    }
    __syncthreads();
    float h = Hin[(size_t)blk * 256 + tid];
    float pd = PD0[(size_t)blk * 16 + ds];
    const float td = TD[(size_t)(b * (DM / 16) + dblk) * 16 + ds];
    for (int l = 0; l < LC; ++l) {
        float dlt = sD[l][ds];
        float uu = sU[l][ds];
        pd += dlt;
        float e = expf(a * dlt);
        h = e * h + dlt * uu * sB[l][n];
        float S = a * (td - pd);
        float corr = 1.0f / (1.0f + 1e-12f * expf(-S));  // overflow -> 0, matches ref
        float contrib = h * corr * sC[l][n];
        contrib += __shfl_xor(contrib, 1);
        contrib += __shfl_xor(contrib, 2);
        contrib += __shfl_xor(contrib, 4);
        contrib += __shfl_xor(contrib, 8);
        if (n == 0) {
            float y = contrib + uu * dp;
            float rr = sR[l][ds];
            float sig = 1.f / (1.f + expf(-rr));
            g[(size_t)(b * LSEQ + l0 + l) * DM + d] = y * rr * sig;
        }
    }
}

extern "C" void kernel_launch(void* const* d_in, const int* in_sizes, int n_in,
                              void* d_out, int out_size, void* d_ws, size_t ws_size,
                              hipStream_t stream) {
    const float* x       = (const float*)d_in[0];
    const float* W_in    = (const float*)d_in[1];
    const float* conv_w  = (const float*)d_in[2];
    const float* conv_b  = (const float*)d_in[3];
    const float* W_x     = (const float*)d_in[4];
    const float* W_delta = (const float*)d_in[5];
    const float* b_delta = (const float*)d_in[6];
    const float* A_log   = (const float*)d_in[7];
    const float* D_param = (const float*)d_in[8];
    const float* W_out   = (const float*)d_in[9];
    float* out = (float*)d_out;
    float* ws  = (float*)d_ws;

    const int R = BSZ * LSEQ;  // 2048

    // Workspace layout — total 7,267,840 floats = 27.7 MiB (Round-1-proven <30.6 MiB).
    // g aliases u (safe: scan_part3 stages u to LDS before overwriting same region).
    float* xr    = ws;                          // R*1536
    float* u     = xr    + (size_t)R * 1536;    // R*768
    float* xp    = u     + (size_t)R * 768;     // R*80
    float* delta = xp    + (size_t)R * 80;      // R*768
    float* g     = u;                           // ALIAS
    float* Eprod = delta + (size_t)R * 768;     // BSZ*48*NC*256
    float* Hend  = Eprod + (size_t)BSZ * 48 * NC * 256;
    float* SDel  = Hend  + (size_t)BSZ * 48 * NC * 256;
    float* TD    = SDel  + (size_t)BSZ * 48 * NC * 16;

    // 1) xr = x @ W_in   (2048 x 1536, K=768) — bf16 MFMA
    gemm_bf16<<<dim3(1536 / 128, R / 128), 256, 0, stream>>>(x, W_in, xr, 768, 768, 1536, 1536);
    // 2) u = silu(causal depthwise conv(xr[:, :768]) + conv_b)
    conv_silu<<<(R * DM) / 256, 256, 0, stream>>>(xr, conv_w, conv_b, u);
    // 3) xp = u @ W_x    (2048 x 80, K=768) — f32 (keeps B/C/delta inputs precise)
    gemm16<<<dim3(80 / 16, R / 16), dim3(16, 16), 0, stream>>>(u, W_x, xp, 768, 768, 80, 80);
    // 4) delta = clip(softplus(xp[:, :48] @ W_delta + b_delta))
    delta_kernel<<<dim3(3, R), 256, 0, stream>>>(xp, W_delta, b_delta, delta);
    // 5) chunked selective scan + D skip + gate with silu(res)
    scan_part1<<<BSZ * (DM / 16) * NC, 256, 0, stream>>>(delta, u, xp, A_log, Eprod, Hend, SDel);
    scan_combine<<<BSZ * (DM / 16), 256, 0, stream>>>(Eprod, Hend, SDel, TD);
    scan_part3<<<BSZ * (DM / 16) * NC, 256, 0, stream>>>(delta, u, xp, xr, A_log, D_param,
                                                         Hend, SDel, TD, g);
    // 6) out = g @ W_out (2048 x 768, K=768) — bf16 MFMA
    gemm_bf16<<<dim3(768 / 128, R / 128), 256, 0, stream>>>(g, W_out, out, 768, 768, 768, 768);
}

// Round 4
// 229.022 us; speedup vs baseline: 3.2359x; 1.1166x over previous
//
#include <hip/hip_runtime.h>
#include <math.h>

#define LSEQ 1024
#define DM   768
#define NS   16
#define DR   48
#define BSZ  2
#define NC   64           // chunks over L
#define LC   (LSEQ/NC)    // 16

typedef __bf16 bf16x4 __attribute__((ext_vector_type(4)));
typedef __bf16 bf16x8 __attribute__((ext_vector_type(8)));
typedef float  f32x4  __attribute__((ext_vector_type(4)));

// ---------------- GEMM: f32 in/out, bf16 MFMA compute, split-column epilogue ----------
// C[M,N] = A[M,K] @ B[K,N]. Tile 128x128, 256 threads = 4 waves (2x2 of 64x64),
// K-step 32, mfma_f32_16x16x32_bf16. Columns >= split go to C1 at (col-split),
// both with leading dim ldc (lets us write xs/res halves to separate buffers).
__global__ __launch_bounds__(256) void gemm_bf16(const float* __restrict__ A,
                                                 const float* __restrict__ B,
                                                 float* __restrict__ C,
                                                 float* __restrict__ C1,
                                                 int split,
                                                 int K, int lda, int ldb, int ldc) {
    __shared__ __align__(16) __bf16 As[128][40];   // As[m][k], row padded to 80 B
    __shared__ __align__(16) __bf16 Bs[128][40];   // Bs[n][k] (transposed in staging)
    const int tid  = threadIdx.x;
    const int lane = tid & 63;
    const int wave = tid >> 6;
    const int wr = (wave >> 1) * 64, wc = (wave & 1) * 64;
    const int r = lane & 15, q = lane >> 4;
    const int m0 = blockIdx.y * 128, n0 = blockIdx.x * 128;

    const int arow = tid >> 3, ac4 = (tid & 7) * 4;
    const int nq = (tid & 7) + (tid >> 6) * 8;   // n-quad
    const int kg = (tid >> 3) & 7;               // k-quad

    f32x4 zero = {0.f, 0.f, 0.f, 0.f};
    f32x4 acc[4][4];
    #pragma unroll
    for (int mt = 0; mt < 4; ++mt)
        #pragma unroll
        for (int nt = 0; nt < 4; ++nt) acc[mt][nt] = zero;

    for (int k0 = 0; k0 < K; k0 += 32) {
        #pragma unroll
        for (int j = 0; j < 4; ++j) {
            int row = arow + 32 * j;
            f32x4 v = *(const f32x4*)(A + (size_t)(m0 + row) * lda + k0 + ac4);
            bf16x4 pk = {(__bf16)v[0], (__bf16)v[1], (__bf16)v[2], (__bf16)v[3]};
            *(bf16x4*)&As[row][ac4] = pk;
        }
        {
            f32x4 bv[4];
            #pragma unroll
            for (int i = 0; i < 4; ++i)
                bv[i] = *(const f32x4*)(B + (size_t)(k0 + kg * 4 + i) * ldb + n0 + nq * 4);
            #pragma unroll
            for (int c = 0; c < 4; ++c) {
                bf16x4 pk = {(__bf16)bv[0][c], (__bf16)bv[1][c],
                             (__bf16)bv[2][c], (__bf16)bv[3][c]};
                *(bf16x4*)&Bs[nq * 4 + c][kg * 4] = pk;
            }
        }
        __syncthreads();
        bf16x8 af[4], bf[4];
        #pragma unroll
        for (int t = 0; t < 4; ++t) {
            af[t] = *(const bf16x8*)&As[wr + t * 16 + r][q * 8];
            bf[t] = *(const bf16x8*)&Bs[wc + t * 16 + r][q * 8];
        }
        #pragma unroll
        for (int mt = 0; mt < 4; ++mt)
            #pragma unroll
            for (int nt = 0; nt < 4; ++nt)
                acc[mt][nt] = __builtin_amdgcn_mfma_f32_16x16x32_bf16(
                    af[mt], bf[nt], acc[mt][nt], 0, 0, 0);
        __syncthreads();
    }
    float* Cd = C;
    int nbase = n0;
    if (n0 >= split) { Cd = C1; nbase = n0 - split; }
    #pragma unroll
    for (int mt = 0; mt < 4; ++mt) {
        #pragma unroll
        for (int nt = 0; nt < 4; ++nt) {
            int col  = nbase + wc + nt * 16 + r;
            int rowb = m0 + wr + mt * 16 + q * 4;
            #pragma unroll
            for (int rr = 0; rr < 4; ++rr)
                Cd[(size_t)(rowb + rr) * ldc + col] = acc[mt][nt][rr];
        }
    }
}

// ---------------- GEMM: 16x16 tile (for small-N xp = u @ W_x), f32 ----------------
__global__ __launch_bounds__(256) void gemm16(const float* __restrict__ A,
                                              const float* __restrict__ B,
                                              float* __restrict__ C,
                                              int K, int lda, int ldb, int ldc) {
    __shared__ float As[16][17];
    __shared__ float Bs[16][17];
    const int tx = threadIdx.x, ty = threadIdx.y;
    const int row = blockIdx.y * 16 + ty;
    const int col = blockIdx.x * 16 + tx;
    float acc = 0.f;
    for (int k0 = 0; k0 < K; k0 += 16) {
        As[ty][tx] = A[(size_t)row * lda + k0 + tx];
        Bs[ty][tx] = B[(size_t)(k0 + ty) * ldb + col];
        __syncthreads();
        #pragma unroll
        for (int kk = 0; kk < 16; ++kk)
            acc += As[ty][kk] * Bs[kk][tx];
        __syncthreads();
    }
    C[(size_t)row * ldc + col] = acc;
}

// ---------------- depthwise causal conv (K=4) + SiLU ----------------
__global__ __launch_bounds__(256) void conv_silu(const float* __restrict__ xs,
                                                 const float* __restrict__ cw,
                                                 const float* __restrict__ cb,
                                                 float* __restrict__ u) {
    const int idx = blockIdx.x * 256 + threadIdx.x;  // r*DM + d
    const int r = idx / DM;
    const int d = idx - r * DM;
    const int l = r & (LSEQ - 1);
    float acc = cb[d];
    #pragma unroll
    for (int k = 0; k < 4; ++k) {
        int ll = l - 3 + k;
        if (ll >= 0)
            acc += xs[(size_t)(r - 3 + k) * DM + d] * cw[d * 4 + k];
    }
    float sig = 1.f / (1.f + expf(-acc));
    u[idx] = acc * sig;
}

// ---------------- delta = clip(softplus(xp[:,:48] @ W_delta + b_delta)) ----------------
__global__ __launch_bounds__(256) void delta_kernel(const float* __restrict__ xp,
                                                    const float* __restrict__ Wd,
                                                    const float* __restrict__ bd,
                                                    float* __restrict__ delta) {
    __shared__ float s[48];
    const int r = blockIdx.y;
    const int c = blockIdx.x * 256 + threadIdx.x;
    if (threadIdx.x < 48) s[threadIdx.x] = xp[(size_t)r * 80 + threadIdx.x];
    __syncthreads();
    float acc = bd[c];
    #pragma unroll
    for (int k = 0; k < 48; ++k)
        acc += s[k] * Wd[k * DM + c];
    float sp = (acc > 20.f) ? acc : log1pf(expf(acc));
    sp = fminf(fmaxf(sp, 1e-4f), 0.1f);
    delta[(size_t)r * DM + c] = sp;
}

// ---------------- chunked selective scan, n-in-registers ----------------
// One thread per (b, d, chunk); 16 n states in registers (no shuffles).
// Eprod/Hend layout: [ch][n][b*DM+d]  -> all accesses lane-coalesced over d.
// SDel layout: [ch][b*DM+d].

// grid = BSZ * (DM/128) * NC = 768 blocks of 128
__global__ __launch_bounds__(128) void scan_part1(const float* __restrict__ delta,
                                                  const float* __restrict__ u,
                                                  const float* __restrict__ xp,
                                                  const float* __restrict__ A_log,
                                                  float* __restrict__ Eprod,
                                                  float* __restrict__ Hend,
                                                  float* __restrict__ SDel) {
    __shared__ float sB[LC][NS];
    const int tid = threadIdx.x;
    const int blk = blockIdx.x;
    const int ch = blk % NC;
    const int dg = (blk / NC) % (DM / 128);
    const int b  = blk / (NC * (DM / 128));
    const int d  = dg * 128 + tid;
    const int l0 = ch * LC;
    const int bd = b * DM + d;

    for (int i = tid; i < LC * NS; i += 128) {
        int l = i >> 4, n = i & 15;
        sB[l][n] = xp[(size_t)(b * LSEQ + l0 + l) * 80 + DR + n];
    }
    float c[NS];
    #pragma unroll
    for (int n = 0; n < NS; ++n) c[n] = -__expf(A_log[d * NS + n]);
    __syncthreads();

    float h[NS], ep[NS];
    #pragma unroll
    for (int n = 0; n < NS; ++n) { h[n] = 0.f; ep[n] = 1.f; }
    float pd = 0.f;
    for (int l = 0; l < LC; ++l) {
        size_t rr = (size_t)(b * LSEQ + l0 + l);
        float dlt = delta[rr * DM + d];
        float uu  = u[rr * DM + d];
        pd += dlt;
        float du = dlt * uu;
        #pragma unroll
        for (int n = 0; n < NS; ++n) {
            float e = __expf(c[n] * dlt);
            h[n]  = e * h[n] + du * sB[l][n];
            ep[n] *= e;
        }
    }
    #pragma unroll
    for (int n = 0; n < NS; ++n) {
        size_t idx = ((size_t)ch * NS + n) * (BSZ * DM) + bd;
        Eprod[idx] = ep[n];
        Hend[idx]  = h[n];
    }
    SDel[(size_t)ch * (BSZ * DM) + bd] = pd;
}

// grid = NS*BSZ*DM/256 = 96 blocks. Overwrites Hend with H_in, SDel with PD0.
__global__ __launch_bounds__(256) void scan_combine(const float* __restrict__ Eprod,
                                                    float* __restrict__ Hend,
                                                    float* __restrict__ SDel,
                                                    float* __restrict__ TD) {
    const int t = blockIdx.x * 256 + threadIdx.x;   // (n, bd) flattened, bd fastest
    const int BD = BSZ * DM;
    float H = 0.f;
    for (int ci = 0; ci < NC; ++ci) {
        size_t idx = (size_t)ci * (NS * BD) + t;
        float e  = Eprod[idx];
        float he = Hend[idx];
        Hend[idx] = H;
        H = e * H + he;
    }
    if (t < BD) {
        float pd = 0.f;
        for (int ci = 0; ci < NC; ++ci) {
            size_t si = (size_t)ci * BD + t;
            float s = SDel[si];
            SDel[si] = pd;
            pd += s;
        }
        TD[t] = pd;
    }
}

// grid = BSZ * (DM/128) * NC. g may alias u: each element is read and written
// only by its owner thread, read-before-write within the same iteration.
__global__ __launch_bounds__(128) void scan_part3(const float* __restrict__ delta,
                                                  const float* __restrict__ u,
                                                  const float* __restrict__ xp,
                                                  const float* __restrict__ res,
                                                  const float* __restrict__ A_log,
                                                  const float* __restrict__ Dp,
                                                  const float* __restrict__ Hin,
                                                  const float* __restrict__ PD0,
                                                  const float* __restrict__ TD,
                                                  float* __restrict__ g) {
    __shared__ float sB[LC][NS];
    __shared__ float sC[LC][NS];
    const int tid = threadIdx.x;
    const int blk = blockIdx.x;
    const int ch = blk % NC;
    const int dg = (blk / NC) % (DM / 128);
    const int b  = blk / (NC * (DM / 128));
    const int d  = dg * 128 + tid;
    const int l0 = ch * LC;
    const int bd = b * DM + d;

    for (int i = tid; i < LC * NS; i += 128) {
        int l = i >> 4, n = i & 15;
        size_t rr = (size_t)(b * LSEQ + l0 + l) * 80;
        sB[l][n] = xp[rr + DR + n];
        sC[l][n] = xp[rr + DR + NS + n];
    }
    float c[NS], h[NS];
    #pragma unroll
    for (int n = 0; n < NS; ++n) {
        c[n] = -__expf(A_log[d * NS + n]);
        h[n] = Hin[((size_t)ch * NS + n) * (BSZ * DM) + bd];
    }
    float pd = PD0[(size_t)ch * (BSZ * DM) + bd];
    const float td = TD[bd];
    const float dp = Dp[d];
    __syncthreads();

    for (int l = 0; l < LC; ++l) {
        size_t rr = (size_t)(b * LSEQ + l0 + l);
        float dlt = delta[rr * DM + d];
        float uu  = u[rr * DM + d];
        float rv  = res[rr * DM + d];
        pd += dlt;
        float du = dlt * uu;
        float x = td - pd;                       // >= 0; exactly 0 at l = L-1
        float y = 0.f;
        #pragma unroll
        for (int n = 0; n < NS; ++n) {
            float e = __expf(c[n] * dlt);
            h[n] = e * h[n] + du * sB[l][n];
            float P = __expf(-c[n] * x);         // exp(-S); overflow->inf
            float den = 1.0f + 1e-12f * P;       // inf -> corr 0, matches ref
            y += h[n] * sC[l][n] * __builtin_amdgcn_rcpf(den);
        }
        y += uu * dp;
        float sig = __builtin_amdgcn_rcpf(1.f + __expf(-rv));
        g[rr * DM + d] = y * rv * sig;
    }
}

extern "C" void kernel_launch(void* const* d_in, const int* in_sizes, int n_in,
                              void* d_out, int out_size, void* d_ws, size_t ws_size,
                              hipStream_t stream) {
    const float* x       = (const float*)d_in[0];
    const float* W_in    = (const float*)d_in[1];
    const float* conv_w  = (const float*)d_in[2];
    const float* conv_b  = (const float*)d_in[3];
    const float* W_x     = (const float*)d_in[4];
    const float* W_delta = (const float*)d_in[5];
    const float* b_delta = (const float*)d_in[6];
    const float* A_log   = (const float*)d_in[7];
    const float* D_param = (const float*)d_in[8];
    const float* W_out   = (const float*)d_in[9];
    float* out = (float*)d_out;
    float* ws  = (float*)d_ws;

    const int R = BSZ * LSEQ;  // 2048

    // Workspace: 6.55M floats = 26.2 MiB (< proven 27.7).
    // Aliases: Eprod <- xs (dead after conv); Hend <- d_out (scratch until final
    // GEMM overwrites); g <- u (per-thread read-before-write in part3).
    float* xs    = ws;                           // R*768
    float* res   = xs    + (size_t)R * DM;       // R*768
    float* u     = res   + (size_t)R * DM;       // R*768
    float* xp    = u     + (size_t)R * DM;       // R*80
    float* delta = xp    + (size_t)R * 80;       // R*768
    float* SDel  = delta + (size_t)R * DM;       // NC*BSZ*DM = 98304
    float* TD    = SDel  + (size_t)NC * BSZ * DM;  // 1536
    float* Eprod = xs;                           // NC*NS*BSZ*DM = 1,572,864 == R*DM
    float* Hend  = out;                          // 1,572,864 == out_size
    float* g     = u;                            // ALIAS

    // 1) xr = x @ W_in, split epilogue -> xs (cols 0..767), res (cols 768..1535)
    gemm_bf16<<<dim3(1536 / 128, R / 128), 256, 0, stream>>>(
        x, W_in, xs, res, 768, 768, 768, 1536, 768);
    // 2) u = silu(causal depthwise conv(xs) + conv_b)
    conv_silu<<<(R * DM) / 256, 256, 0, stream>>>(xs, conv_w, conv_b, u);
    // 3) xp = u @ W_x
    gemm16<<<dim3(80 / 16, R / 16), dim3(16, 16), 0, stream>>>(u, W_x, xp, 768, 768, 80, 80);
    // 4) delta
    delta_kernel<<<dim3(3, R), 256, 0, stream>>>(xp, W_delta, b_delta, delta);
    // 5) chunked scan (xs dead -> Eprod; d_out scratch -> Hend)
    scan_part1<<<BSZ * (DM / 128) * NC, 128, 0, stream>>>(delta, u, xp, A_log, Eprod, Hend, SDel);
    scan_combine<<<(NS * BSZ * DM) / 256, 256, 0, stream>>>(Eprod, Hend, SDel, TD);
    scan_part3<<<BSZ * (DM / 128) * NC, 128, 0, stream>>>(delta, u, xp, res, A_log, D_param,
                                                          Hend, SDel, TD, g);
    // 6) out = g @ W_out
    gemm_bf16<<<dim3(768 / 128, R / 128), 256, 0, stream>>>(
        g, W_out, out, out, 1 << 30, 768, 768, 768, 768);
}

// Round 5
// 213.549 us; speedup vs baseline: 3.4704x; 1.0725x over previous
//
#include <hip/hip_runtime.h>
#include <math.h>

#define LSEQ 1024
#define DM   768
#define NS   16
#define DR   48
#define BSZ  2
#define NC   64           // chunks over L
#define LC   (LSEQ/NC)    // 16

typedef __bf16 bf16x4 __attribute__((ext_vector_type(4)));
typedef __bf16 bf16x8 __attribute__((ext_vector_type(8)));
typedef float  f32x4  __attribute__((ext_vector_type(4)));

// ---------------- GEMM: f32 in/out, bf16 MFMA, reg-prefetch, split epilogue --------
// C[M,N] = A[M,K] @ B[K,N]. Tile 128x128, 256 thr = 4 waves (2x2 of 64x64), K-step 32.
// Global loads for tile k+1 are issued before the MFMA block of tile k, so the
// vmcnt wait (at the LDS-store point of the next iteration) lands after compute.
__global__ __launch_bounds__(256) void gemm_bf16(const float* __restrict__ A,
                                                 const float* __restrict__ B,
                                                 float* __restrict__ C,
                                                 float* __restrict__ C1,
                                                 int split,
                                                 int K, int lda, int ldb, int ldc) {
    __shared__ __align__(16) __bf16 As[128][40];   // As[m][k], row padded to 80 B
    __shared__ __align__(16) __bf16 Bs[128][40];   // Bs[n][k] (transposed in staging)
    const int tid  = threadIdx.x;
    const int lane = tid & 63;
    const int wave = tid >> 6;
    const int wr = (wave >> 1) * 64, wc = (wave & 1) * 64;
    const int r = lane & 15, q = lane >> 4;
    const int m0 = blockIdx.y * 128, n0 = blockIdx.x * 128;

    const int arow = tid >> 3, ac4 = (tid & 7) * 4;
    const int nq = (tid & 7) + (tid >> 6) * 8;   // n-quad
    const int kg = (tid >> 3) & 7;               // k-quad

    f32x4 zero = {0.f, 0.f, 0.f, 0.f};
    f32x4 acc[4][4];
    #pragma unroll
    for (int mt = 0; mt < 4; ++mt)
        #pragma unroll
        for (int nt = 0; nt < 4; ++nt) acc[mt][nt] = zero;

    f32x4 a_pf[4], b_pf[4];
    #pragma unroll
    for (int j = 0; j < 4; ++j)
        a_pf[j] = *(const f32x4*)(A + (size_t)(m0 + arow + 32 * j) * lda + ac4);
    #pragma unroll
    for (int i = 0; i < 4; ++i)
        b_pf[i] = *(const f32x4*)(B + (size_t)(kg * 4 + i) * ldb + n0 + nq * 4);

    const int KT = K / 32;
    for (int kt = 0; kt < KT; ++kt) {
        #pragma unroll
        for (int j = 0; j < 4; ++j) {
            bf16x4 pk = {(__bf16)a_pf[j][0], (__bf16)a_pf[j][1],
                         (__bf16)a_pf[j][2], (__bf16)a_pf[j][3]};
            *(bf16x4*)&As[arow + 32 * j][ac4] = pk;
        }
        #pragma unroll
        for (int c = 0; c < 4; ++c) {
            bf16x4 pk = {(__bf16)b_pf[0][c], (__bf16)b_pf[1][c],
                         (__bf16)b_pf[2][c], (__bf16)b_pf[3][c]};
            *(bf16x4*)&Bs[nq * 4 + c][kg * 4] = pk;
        }
        __syncthreads();
        if (kt + 1 < KT) {
            int k0 = (kt + 1) * 32;
            #pragma unroll
            for (int j = 0; j < 4; ++j)
                a_pf[j] = *(const f32x4*)(A + (size_t)(m0 + arow + 32 * j) * lda + k0 + ac4);
            #pragma unroll
            for (int i = 0; i < 4; ++i)
                b_pf[i] = *(const f32x4*)(B + (size_t)(k0 + kg * 4 + i) * ldb + n0 + nq * 4);
        }
        bf16x8 af[4], bf[4];
        #pragma unroll
        for (int t = 0; t < 4; ++t) {
            af[t] = *(const bf16x8*)&As[wr + t * 16 + r][q * 8];
            bf[t] = *(const bf16x8*)&Bs[wc + t * 16 + r][q * 8];
        }
        #pragma unroll
        for (int mt = 0; mt < 4; ++mt)
            #pragma unroll
            for (int nt = 0; nt < 4; ++nt)
                acc[mt][nt] = __builtin_amdgcn_mfma_f32_16x16x32_bf16(
                    af[mt], bf[nt], acc[mt][nt], 0, 0, 0);
        __syncthreads();
    }
    float* Cd = C;
    int nbase = n0;
    if (n0 >= split) { Cd = C1; nbase = n0 - split; }
    #pragma unroll
    for (int mt = 0; mt < 4; ++mt) {
        #pragma unroll
        for (int nt = 0; nt < 4; ++nt) {
            int col  = nbase + wc + nt * 16 + r;
            int rowb = m0 + wr + mt * 16 + q * 4;
            #pragma unroll
            for (int rr = 0; rr < 4; ++rr)
                Cd[(size_t)(rowb + rr) * ldc + col] = acc[mt][nt][rr];
        }
    }
}

// ---------------- xp = u @ W_x (2048 x 80, K=768), bf16 MFMA ----------------
// M-tile 64 (4 waves x 16 rows), N=80 = 5 MFMA col-tiles per wave, grid 32.
__global__ __launch_bounds__(256) void gemm_wx(const float* __restrict__ U,
                                               const float* __restrict__ Wx,
                                               float* __restrict__ xp) {
    __shared__ __align__(16) __bf16 As2[64][40];
    __shared__ __align__(16) __bf16 Ws[80][40];
    const int tid  = threadIdx.x;
    const int lane = tid & 63;
    const int wave = tid >> 6;
    const int r = lane & 15, q = lane >> 4;
    const int m0 = blockIdx.x * 64;
    const int arow = tid >> 2, ak8 = (tid & 3) * 8;
    const int nq = tid % 20, kq = tid / 20;      // W transpose task (tid<160)

    f32x4 zero = {0.f, 0.f, 0.f, 0.f};
    f32x4 acc[5];
    #pragma unroll
    for (int nt = 0; nt < 5; ++nt) acc[nt] = zero;

    f32x4 a_pf0, a_pf1, w_pf[4];
    a_pf0 = *(const f32x4*)(U + (size_t)(m0 + arow) * DM + ak8);
    a_pf1 = *(const f32x4*)(U + (size_t)(m0 + arow) * DM + ak8 + 4);
    if (tid < 160) {
        #pragma unroll
        for (int i = 0; i < 4; ++i)
            w_pf[i] = *(const f32x4*)(Wx + (size_t)(kq * 4 + i) * 80 + nq * 4);
    }

    for (int kt = 0; kt < 24; ++kt) {
        bf16x4 p0 = {(__bf16)a_pf0[0], (__bf16)a_pf0[1], (__bf16)a_pf0[2], (__bf16)a_pf0[3]};
        bf16x4 p1 = {(__bf16)a_pf1[0], (__bf16)a_pf1[1], (__bf16)a_pf1[2], (__bf16)a_pf1[3]};
        *(bf16x4*)&As2[arow][ak8]     = p0;
        *(bf16x4*)&As2[arow][ak8 + 4] = p1;
        if (tid < 160) {
            #pragma unroll
            for (int c = 0; c < 4; ++c) {
                bf16x4 pk = {(__bf16)w_pf[0][c], (__bf16)w_pf[1][c],
                             (__bf16)w_pf[2][c], (__bf16)w_pf[3][c]};
                *(bf16x4*)&Ws[nq * 4 + c][kq * 4] = pk;
            }
        }
        __syncthreads();
        if (kt + 1 < 24) {
            int k0 = (kt + 1) * 32;
            a_pf0 = *(const f32x4*)(U + (size_t)(m0 + arow) * DM + k0 + ak8);
            a_pf1 = *(const f32x4*)(U + (size_t)(m0 + arow) * DM + k0 + ak8 + 4);
            if (tid < 160) {
                #pragma unroll
                for (int i = 0; i < 4; ++i)
                    w_pf[i] = *(const f32x4*)(Wx + (size_t)(k0 + kq * 4 + i) * 80 + nq * 4);
            }
        }
        bf16x8 af = *(const bf16x8*)&As2[wave * 16 + r][q * 8];
        #pragma unroll
        for (int nt = 0; nt < 5; ++nt) {
            bf16x8 bfr = *(const bf16x8*)&Ws[nt * 16 + r][q * 8];
            acc[nt] = __builtin_amdgcn_mfma_f32_16x16x32_bf16(af, bfr, acc[nt], 0, 0, 0);
        }
        __syncthreads();
    }
    #pragma unroll
    for (int nt = 0; nt < 5; ++nt) {
        int col  = nt * 16 + r;
        int rowb = m0 + wave * 16 + q * 4;
        #pragma unroll
        for (int rr = 0; rr < 4; ++rr)
            xp[(size_t)(rowb + rr) * 80 + col] = acc[nt][rr];
    }
}

// ---------------- delta = clip(softplus(xp[:,:48] @ W_delta + b_delta)) ------------
// bf16 MFMA 128x128 tile, K=48 zero-padded to 64 (2 K-steps), fused epilogue.
__global__ __launch_bounds__(256) void gemm_delta(const float* __restrict__ xp,
                                                  const float* __restrict__ Wd,
                                                  const float* __restrict__ bd,
                                                  float* __restrict__ delta) {
    __shared__ __align__(16) __bf16 As[128][40];
    __shared__ __align__(16) __bf16 Bs[128][40];
    const int tid  = threadIdx.x;
    const int lane = tid & 63;
    const int wave = tid >> 6;
    const int wr = (wave >> 1) * 64, wc = (wave & 1) * 64;
    const int r = lane & 15, q = lane >> 4;
    const int m0 = blockIdx.y * 128, n0 = blockIdx.x * 128;
    const int arow = tid >> 1, ak16 = (tid & 1) * 16;
    const int nq = tid & 31, kq = tid >> 5;

    f32x4 zero = {0.f, 0.f, 0.f, 0.f};
    f32x4 acc[4][4];
    #pragma unroll
    for (int mt = 0; mt < 4; ++mt)
        #pragma unroll
        for (int nt = 0; nt < 4; ++nt) acc[mt][nt] = zero;

    for (int k0 = 0; k0 < 64; k0 += 32) {
        #pragma unroll
        for (int j = 0; j < 4; ++j) {
            int k = k0 + ak16 + j * 4;
            f32x4 v = (k < DR) ? *(const f32x4*)(xp + (size_t)(m0 + arow) * 80 + k) : zero;
            bf16x4 pk = {(__bf16)v[0], (__bf16)v[1], (__bf16)v[2], (__bf16)v[3]};
            *(bf16x4*)&As[arow][ak16 + j * 4] = pk;
        }
        {
            f32x4 bv[4];
            #pragma unroll
            for (int i = 0; i < 4; ++i) {
                int k = k0 + kq * 4 + i;
                bv[i] = (k < DR) ? *(const f32x4*)(Wd + (size_t)k * DM + n0 + nq * 4) : zero;
            }
            #pragma unroll
            for (int c = 0; c < 4; ++c) {
                bf16x4 pk = {(__bf16)bv[0][c], (__bf16)bv[1][c],
                             (__bf16)bv[2][c], (__bf16)bv[3][c]};
                *(bf16x4*)&Bs[nq * 4 + c][kq * 4] = pk;
            }
        }
        __syncthreads();
        bf16x8 af[4], bf[4];
        #pragma unroll
        for (int t = 0; t < 4; ++t) {
            af[t] = *(const bf16x8*)&As[wr + t * 16 + r][q * 8];
            bf[t] = *(const bf16x8*)&Bs[wc + t * 16 + r][q * 8];
        }
        #pragma unroll
        for (int mt = 0; mt < 4; ++mt)
            #pragma unroll
            for (int nt = 0; nt < 4; ++nt)
                acc[mt][nt] = __builtin_amdgcn_mfma_f32_16x16x32_bf16(
                    af[mt], bf[nt], acc[mt][nt], 0, 0, 0);
        __syncthreads();
    }
    #pragma unroll
    for (int mt = 0; mt < 4; ++mt) {
        #pragma unroll
        for (int nt = 0; nt < 4; ++nt) {
            int col  = n0 + wc + nt * 16 + r;
            int rowb = m0 + wr + mt * 16 + q * 4;
            float bcol = bd[col];
            #pragma unroll
            for (int rr = 0; rr < 4; ++rr) {
                float z = acc[mt][nt][rr] + bcol;
                float sp = (z > 20.f) ? z : log1pf(expf(z));
                sp = fminf(fmaxf(sp, 1e-4f), 0.1f);
                delta[(size_t)(rowb + rr) * DM + col] = sp;
            }
        }
    }
}

// ---------------- depthwise causal conv (K=4) + SiLU ----------------
__global__ __launch_bounds__(256) void conv_silu(const float* __restrict__ xs,
                                                 const float* __restrict__ cw,
                                                 const float* __restrict__ cb,
                                                 float* __restrict__ u) {
    const int idx = blockIdx.x * 256 + threadIdx.x;  // r*DM + d
    const int r = idx / DM;
    const int d = idx - r * DM;
    const int l = r & (LSEQ - 1);
    float acc = cb[d];
    #pragma unroll
    for (int k = 0; k < 4; ++k) {
        int ll = l - 3 + k;
        if (ll >= 0)
            acc += xs[(size_t)(r - 3 + k) * DM + d] * cw[d * 4 + k];
    }
    float sig = 1.f / (1.f + expf(-acc));
    u[idx] = acc * sig;
}

// ---------------- chunked selective scan, n-in-registers ----------------
// grid = BSZ * (DM/128) * NC = 768 blocks of 128
__global__ __launch_bounds__(128) void scan_part1(const float* __restrict__ delta,
                                                  const float* __restrict__ u,
                                                  const float* __restrict__ xp,
                                                  const float* __restrict__ A_log,
                                                  float* __restrict__ Eprod,
                                                  float* __restrict__ Hend,
                                                  float* __restrict__ SDel) {
    __shared__ float sB[LC][NS];
    const int tid = threadIdx.x;
    const int blk = blockIdx.x;
    const int ch = blk % NC;
    const int dg = (blk / NC) % (DM / 128);
    const int b  = blk / (NC * (DM / 128));
    const int d  = dg * 128 + tid;
    const int l0 = ch * LC;
    const int bd = b * DM + d;

    for (int i = tid; i < LC * NS; i += 128) {
        int l = i >> 4, n = i & 15;
        sB[l][n] = xp[(size_t)(b * LSEQ + l0 + l) * 80 + DR + n];
    }
    float c[NS];
    #pragma unroll
    for (int n = 0; n < NS; ++n) c[n] = -__expf(A_log[d * NS + n]);
    __syncthreads();

    float h[NS], ep[NS];
    #pragma unroll
    for (int n = 0; n < NS; ++n) { h[n] = 0.f; ep[n] = 1.f; }
    float pd = 0.f;
    for (int l = 0; l < LC; ++l) {
        size_t rr = (size_t)(b * LSEQ + l0 + l);
        float dlt = delta[rr * DM + d];
        float uu  = u[rr * DM + d];
        pd += dlt;
        float du = dlt * uu;
        #pragma unroll
        for (int n = 0; n < NS; ++n) {
            float e = __expf(c[n] * dlt);
            h[n]  = e * h[n] + du * sB[l][n];
            ep[n] *= e;
        }
    }
    #pragma unroll
    for (int n = 0; n < NS; ++n) {
        size_t idx = ((size_t)ch * NS + n) * (BSZ * DM) + bd;
        Eprod[idx] = ep[n];
        Hend[idx]  = h[n];
    }
    SDel[(size_t)ch * (BSZ * DM) + bd] = pd;
}

// grid = 96 blocks. 8-wide load groups: 64 dependent latencies -> 8.
__global__ __launch_bounds__(256) void scan_combine(const float* __restrict__ Eprod,
                                                    float* __restrict__ Hend,
                                                    float* __restrict__ SDel,
                                                    float* __restrict__ TD) {
    const int t = blockIdx.x * 256 + threadIdx.x;   // (n, bd) flattened, bd fastest
    const int BD = BSZ * DM;
    float H = 0.f;
    for (int cg = 0; cg < NC; cg += 8) {
        float e[8], he[8];
        #pragma unroll
        for (int j = 0; j < 8; ++j) {
            size_t idx = (size_t)(cg + j) * (NS * BD) + t;
            e[j]  = Eprod[idx];
            he[j] = Hend[idx];
        }
        #pragma unroll
        for (int j = 0; j < 8; ++j) {
            size_t idx = (size_t)(cg + j) * (NS * BD) + t;
            Hend[idx] = H;
            H = e[j] * H + he[j];
        }
    }
    if (t < BD) {
        float pd = 0.f;
        for (int cg = 0; cg < NC; cg += 8) {
            float s[8];
            #pragma unroll
            for (int j = 0; j < 8; ++j) s[j] = SDel[(size_t)(cg + j) * BD + t];
            #pragma unroll
            for (int j = 0; j < 8; ++j) {
                SDel[(size_t)(cg + j) * BD + t] = pd;
                pd += s[j];
            }
        }
        TD[t] = pd;
    }
}

// grid = BSZ * (DM/128) * NC. g aliases u (per-thread read-before-write).
__global__ __launch_bounds__(128) void scan_part3(const float* __restrict__ delta,
                                                  const float* __restrict__ u,
                                                  const float* __restrict__ xp,
                                                  const float* __restrict__ res,
                                                  const float* __restrict__ A_log,
                                                  const float* __restrict__ Dp,
                                                  const float* __restrict__ Hin,
                                                  const float* __restrict__ PD0,
                                                  const float* __restrict__ TD,
                                                  float* __restrict__ g) {
    __shared__ float sB[LC][NS];
    __shared__ float sC[LC][NS];
    const int tid = threadIdx.x;
    const int blk = blockIdx.x;
    const int ch = blk % NC;
    const int dg = (blk / NC) % (DM / 128);
    const int b  = blk / (NC * (DM / 128));
    const int d  = dg * 128 + tid;
    const int l0 = ch * LC;
    const int bd = b * DM + d;

    for (int i = tid; i < LC * NS; i += 128) {
        int l = i >> 4, n = i & 15;
        size_t rr = (size_t)(b * LSEQ + l0 + l) * 80;
        sB[l][n] = xp[rr + DR + n];
        sC[l][n] = xp[rr + DR + NS + n];
    }
    float c[NS], h[NS];
    #pragma unroll
    for (int n = 0; n < NS; ++n) {
        c[n] = -__expf(A_log[d * NS + n]);
        h[n] = Hin[((size_t)ch * NS + n) * (BSZ * DM) + bd];
    }
    float pd = PD0[(size_t)ch * (BSZ * DM) + bd];
    const float td = TD[bd];
    const float dp = Dp[d];
    __syncthreads();

    for (int l = 0; l < LC; ++l) {
        size_t rr = (size_t)(b * LSEQ + l0 + l);
        float dlt = delta[rr * DM + d];
        float uu  = u[rr * DM + d];
        float rv  = res[rr * DM + d];
        pd += dlt;
        float du = dlt * uu;
        float x = td - pd;                       // >= 0; exactly 0 at l = L-1
        float y = 0.f;
        #pragma unroll
        for (int n = 0; n < NS; ++n) {
            float e = __expf(c[n] * dlt);
            h[n] = e * h[n] + du * sB[l][n];
            float P = __expf(-c[n] * x);         // exp(-S); overflow->inf
            float den = 1.0f + 1e-12f * P;       // inf -> corr 0, matches ref
            y += h[n] * sC[l][n] * __builtin_amdgcn_rcpf(den);
        }
        y += uu * dp;
        float sig = __builtin_amdgcn_rcpf(1.f + __expf(-rv));
        g[rr * DM + d] = y * rv * sig;
    }
}

extern "C" void kernel_launch(void* const* d_in, const int* in_sizes, int n_in,
                              void* d_out, int out_size, void* d_ws, size_t ws_size,
                              hipStream_t stream) {
    const float* x       = (const float*)d_in[0];
    const float* W_in    = (const float*)d_in[1];
    const float* conv_w  = (const float*)d_in[2];
    const float* conv_b  = (const float*)d_in[3];
    const float* W_x     = (const float*)d_in[4];
    const float* W_delta = (const float*)d_in[5];
    const float* b_delta = (const float*)d_in[6];
    const float* A_log   = (const float*)d_in[7];
    const float* D_param = (const float*)d_in[8];
    const float* W_out   = (const float*)d_in[9];
    float* out = (float*)d_out;
    float* ws  = (float*)d_ws;

    const int R = BSZ * LSEQ;  // 2048

    // Workspace: 26.2 MiB. Aliases: Eprod <- xs (dead after conv);
    // Hend <- d_out (scratch until final GEMM); g <- u.
    float* xs    = ws;                           // R*768
    float* res   = xs    + (size_t)R * DM;       // R*768
    float* u     = res   + (size_t)R * DM;       // R*768
    float* xp    = u     + (size_t)R * DM;       // R*80
    float* delta = xp    + (size_t)R * 80;       // R*768
    float* SDel  = delta + (size_t)R * DM;       // NC*BSZ*DM
    float* TD    = SDel  + (size_t)NC * BSZ * DM;  // BSZ*DM
    float* Eprod = xs;                           // ALIAS (NC*NS*BSZ*DM == R*DM)
    float* Hend  = out;                          // ALIAS (== out_size)
    float* g     = u;                            // ALIAS

    // 1) xr = x @ W_in, split epilogue -> xs (cols 0..767), res (cols 768..1535)
    gemm_bf16<<<dim3(1536 / 128, R / 128), 256, 0, stream>>>(
        x, W_in, xs, res, 768, 768, 768, 1536, 768);
    // 2) u = silu(causal depthwise conv(xs) + conv_b)
    conv_silu<<<(R * DM) / 256, 256, 0, stream>>>(xs, conv_w, conv_b, u);
    // 3) xp = u @ W_x (bf16 MFMA, N=80)
    gemm_wx<<<R / 64, 256, 0, stream>>>(u, W_x, xp);
    // 4) delta (bf16 MFMA, K=48 padded, fused softplus epilogue)
    gemm_delta<<<dim3(DM / 128, R / 128), 256, 0, stream>>>(xp, W_delta, b_delta, delta);
    // 5) chunked scan
    scan_part1<<<BSZ * (DM / 128) * NC, 128, 0, stream>>>(delta, u, xp, A_log, Eprod, Hend, SDel);
    scan_combine<<<(NS * BSZ * DM) / 256, 256, 0, stream>>>(Eprod, Hend, SDel, TD);
    scan_part3<<<BSZ * (DM / 128) * NC, 128, 0, stream>>>(delta, u, xp, res, A_log, D_param,
                                                          Hend, SDel, TD, g);
    // 6) out = g @ W_out
    gemm_bf16<<<dim3(768 / 128, R / 128), 256, 0, stream>>>(
        g, W_out, out, out, 1 << 30, 768, 768, 768, 768);
}